// Round 3
// baseline (77.132 us; speedup 1.0000x reference)
//
#include <hip/hip_runtime.h>
#include <hip/hip_bf16.h>

#define NB 32
#define NN 1024
#define FF 128

typedef __attribute__((ext_vector_type(8))) short short8;
typedef __attribute__((ext_vector_type(4))) float f32x4;
typedef __attribute__((ext_vector_type(2))) unsigned long long u64x2;

static __device__ __forceinline__ unsigned short f2bf(float x) {
  unsigned int u = __float_as_uint(x);
  u += 0x7fffu + ((u >> 16) & 1u);
  return (unsigned short)(u >> 16);
}

static __device__ __forceinline__ unsigned long long pack4bf(float a, float b, float c, float d) {
  return (unsigned long long)f2bf(a)
       | ((unsigned long long)f2bf(b) << 16)
       | ((unsigned long long)f2bf(c) << 32)
       | ((unsigned long long)f2bf(d) << 48);
}

// ---- k1: pure column sums of A (no diag; k2 adds +1). Leaves A L3-resident. --
__global__ __launch_bounds__(256) void k1_colsum(const float* __restrict__ A,
                                                 float* __restrict__ partial) {
  int t = threadIdx.x;          // 0..255 -> columns 4t..4t+3
  int s = blockIdx.x;           // 0..15  -> rows s*64..s*64+63
  int b = blockIdx.y;           // 0..31
  const float* base = A + (size_t)b * NN * NN + (size_t)(s * 64) * NN + (t << 2);
  float4 sum = make_float4(0.f, 0.f, 0.f, 0.f);
  #pragma unroll 8
  for (int i = 0; i < 64; ++i) {
    float4 v = *reinterpret_cast<const float4*>(base + (size_t)i * NN);
    sum.x += v.x; sum.y += v.y; sum.z += v.z; sum.w += v.w;
  }
  *reinterpret_cast<float4*>(partial + (((b << 4) + s) << 10) + (t << 2)) = sum;
}

// ---- k2: inv_sqrt_d (d = 1 + colsum), zero pooled, Wt = bf16(W^T) ------------
__global__ void k2_finalize(const float* __restrict__ partial, const float* __restrict__ W,
                            float* __restrict__ isd, float* __restrict__ pooled,
                            unsigned short* __restrict__ Wt) {
  int idx = blockIdx.x * 256 + threadIdx.x;  // 0..32767
  int b = idx >> 10, j = idx & 1023;
  float d = 1.0f;
  #pragma unroll
  for (int s = 0; s < 16; ++s) d += partial[(((b << 4) + s) << 10) + j];
  isd[idx] = rsqrtf(d);
  if (idx < 4096) pooled[idx] = 0.f;
  if (idx < 16384) {
    int o = idx >> 7, k = idx & 127;
    Wt[idx] = f2bf(W[k * FF + o]);   // Wt[o][k] = W[k][o]
  }
}

// ---- k3: HWpT[b][o][j] = bf16( isd[b,j] * sum_k W[k][o]*H[b][j][k] ) ---------
__global__ __launch_bounds__(512) void k3_hw(const float* __restrict__ H,
                                             const unsigned short* __restrict__ Wt,
                                             const float* __restrict__ isd,
                                             unsigned short* __restrict__ HWpT) {
  __shared__ unsigned short Ws[128][136];
  __shared__ unsigned short Hs[128][136];
  int jblk = blockIdx.x;  // 0..7
  int b = blockIdx.y;     // 0..31
  int tid = threadIdx.x, wave = tid >> 6, lane = tid & 63;

  {
    int r = tid >> 4, c = (tid & 15) << 3;
    #pragma unroll
    for (int p = 0; p < 4; ++p) {
      int row = r + (p << 5);
      *reinterpret_cast<short8*>(&Ws[row][c]) =
          *reinterpret_cast<const short8*>(Wt + row * FF + c);
    }
  }
  {
    int r = tid >> 5, c = (tid & 31) << 2;
    const float* Hbase = H + (size_t)b * NN * FF + (size_t)(jblk * 128) * FF;
    #pragma unroll
    for (int p = 0; p < 8; ++p) {
      int row = r + (p << 4);
      const float4 v = *reinterpret_cast<const float4*>(Hbase + (size_t)row * FF + c);
      *reinterpret_cast<unsigned long long*>(&Hs[row][c]) = pack4bf(v.x, v.y, v.z, v.w);
    }
  }
  __syncthreads();

  f32x4 acc[8];
  #pragma unroll
  for (int i = 0; i < 8; ++i) acc[i] = (f32x4){0.f, 0.f, 0.f, 0.f};

  int mrow = (wave << 4) + (lane & 15);
  int koff = (lane >> 4) << 3;
  #pragma unroll
  for (int kk = 0; kk < 4; ++kk) {
    short8 af = *reinterpret_cast<const short8*>(&Ws[mrow][(kk << 5) + koff]);
    #pragma unroll
    for (int nf = 0; nf < 8; ++nf) {
      short8 bf = *reinterpret_cast<const short8*>(&Hs[(nf << 4) + (lane & 15)][(kk << 5) + koff]);
      acc[nf] = __builtin_amdgcn_mfma_f32_16x16x32_bf16(af, bf, acc[nf], 0, 0, 0);
    }
  }

  int fbase = (wave << 4) + ((lane >> 4) << 2);
  #pragma unroll
  for (int nf = 0; nf < 8; ++nf) {
    int j = (jblk << 7) + (nf << 4) + (lane & 15);
    float sc = isd[(b << 10) + j];
    size_t outb = (size_t)b * FF * NN + (size_t)j;
    #pragma unroll
    for (int r = 0; r < 4; ++r) {
      HWpT[outb + (size_t)(fbase + r) * NN] = f2bf(acc[nf][r] * sc);
    }
  }
}

// ---- k4: h = relu(isd_i * (Atilde @ HWp')[i,f] + bias_f), fused sum-pool -----
// A read fp32 from L3 (warmed by k1), reg-convert -> swizzled LDS.
// B (HWpT) fragments loaded straight from global (L2-resident), no LDS.
__global__ __launch_bounds__(256) void k4_gcn(const float* __restrict__ A,
                                              const unsigned short* __restrict__ HWpT,
                                              const float* __restrict__ isd,
                                              const float* __restrict__ bias,
                                              float* __restrict__ pooled) {
  __shared__ __align__(1024) unsigned short As[64 * 64];   // 8 KB, XOR-swizzled
  int iblk = blockIdx.x;  // 0..15
  int b = blockIdx.y;     // 0..31
  int tid = threadIdx.x, wave = tid >> 6, lane = tid & 63;
  int wm = wave >> 1, wn = wave & 1;
  int i0 = iblk * 64;
  int l15 = lane & 15, q = lane >> 4;

  const float* Abase = A + (size_t)b * NN * NN + (size_t)i0 * NN;
  const unsigned short* Bbase = HWpT + (size_t)b * FF * NN
                              + (size_t)((wn << 6) + l15) * NN + (q << 3);

  f32x4 acc[2][4];
  #pragma unroll
  for (int m = 0; m < 2; ++m)
    #pragma unroll
    for (int n = 0; n < 4; ++n) acc[m][n] = (f32x4){0.f, 0.f, 0.f, 0.f};

  // A staging: thread -> row sr, 16 floats at col sc
  int sr = tid >> 2;
  int sc = (tid & 3) << 4;
  const float* aRow = Abase + (size_t)sr * NN + sc;
  int swzW = (sr & 7) << 4;
  int wb0 = (sr * 128 + sc * 2) ^ swzW;        // bytes for elems 0..7
  int wb1 = (sr * 128 + sc * 2 + 16) ^ swzW;   // bytes for elems 8..15
  int drow = i0 + sr - sc;                      // diag elem index = drow - k0

  int mrow0 = (wm << 5) + l15;
  int swzR = (mrow0 & 7) << 4;
  int q16 = q << 4;

  for (int k0 = 0; k0 < NN; k0 += 64) {
    // issue loads early
    float4 v0 = *reinterpret_cast<const float4*>(aRow + k0);
    float4 v1 = *reinterpret_cast<const float4*>(aRow + k0 + 4);
    float4 v2 = *reinterpret_cast<const float4*>(aRow + k0 + 8);
    float4 v3 = *reinterpret_cast<const float4*>(aRow + k0 + 12);
    short8 bfr[4][2];
    #pragma unroll
    for (int nf = 0; nf < 4; ++nf) {
      #pragma unroll
      for (int kk = 0; kk < 2; ++kk) {
        bfr[nf][kk] = *reinterpret_cast<const short8*>(Bbase + (size_t)(nf << 4) * NN + k0 + (kk << 5));
      }
    }
    __syncthreads();   // previous step's frag reads done
    {
      int dp = drow - k0;   // add identity at element dp if 0<=dp<16
      v0.x += (dp == 0)  ? 1.f : 0.f;  v0.y += (dp == 1)  ? 1.f : 0.f;
      v0.z += (dp == 2)  ? 1.f : 0.f;  v0.w += (dp == 3)  ? 1.f : 0.f;
      v1.x += (dp == 4)  ? 1.f : 0.f;  v1.y += (dp == 5)  ? 1.f : 0.f;
      v1.z += (dp == 6)  ? 1.f : 0.f;  v1.w += (dp == 7)  ? 1.f : 0.f;
      v2.x += (dp == 8)  ? 1.f : 0.f;  v2.y += (dp == 9)  ? 1.f : 0.f;
      v2.z += (dp == 10) ? 1.f : 0.f;  v2.w += (dp == 11) ? 1.f : 0.f;
      v3.x += (dp == 12) ? 1.f : 0.f;  v3.y += (dp == 13) ? 1.f : 0.f;
      v3.z += (dp == 14) ? 1.f : 0.f;  v3.w += (dp == 15) ? 1.f : 0.f;
      u64x2 w0, w1;
      w0[0] = pack4bf(v0.x, v0.y, v0.z, v0.w);
      w0[1] = pack4bf(v1.x, v1.y, v1.z, v1.w);
      w1[0] = pack4bf(v2.x, v2.y, v2.z, v2.w);
      w1[1] = pack4bf(v3.x, v3.y, v3.z, v3.w);
      *reinterpret_cast<u64x2*>((char*)As + wb0) = w0;
      *reinterpret_cast<u64x2*>((char*)As + wb1) = w1;
    }
    __syncthreads();   // staged tile visible
    #pragma unroll
    for (int kk = 0; kk < 2; ++kk) {
      short8 af[2];
      #pragma unroll
      for (int mr = 0; mr < 2; ++mr) {
        int off = (((mrow0 + (mr << 4)) << 7) + (kk << 6) + q16) ^ swzR;
        af[mr] = *reinterpret_cast<const short8*>((const char*)As + off);
      }
      #pragma unroll
      for (int mr = 0; mr < 2; ++mr)
        #pragma unroll
        for (int nf = 0; nf < 4; ++nf)
          acc[mr][nf] = __builtin_amdgcn_mfma_f32_16x16x32_bf16(af[mr], bfr[nf][kk], acc[mr][nf], 0, 0, 0);
    }
  }

  // epilogue: scale rows by isd_i, +bias, relu, sum over rows, atomic into pooled
  #pragma unroll
  for (int mr = 0; mr < 2; ++mr) {
    int irow = i0 + (wm << 5) + (mr << 4) + (q << 2);
    float sc0 = isd[(b << 10) + irow];
    float sc1 = isd[(b << 10) + irow + 1];
    float sc2 = isd[(b << 10) + irow + 2];
    float sc3 = isd[(b << 10) + irow + 3];
    #pragma unroll
    for (int nf = 0; nf < 4; ++nf) {
      int f = (wn << 6) + (nf << 4) + l15;
      float bi = bias[f];
      float s = fmaxf(acc[mr][nf][0] * sc0 + bi, 0.f)
              + fmaxf(acc[mr][nf][1] * sc1 + bi, 0.f)
              + fmaxf(acc[mr][nf][2] * sc2 + bi, 0.f)
              + fmaxf(acc[mr][nf][3] * sc3 + bi, 0.f);
      s += __shfl_xor(s, 16);
      s += __shfl_xor(s, 32);
      if (lane < 16) atomicAdd(&pooled[(b << 7) + f], s);
    }
  }
}

// ---- k5: out[b] = sum_f pooled[b][f]*fc_w[f] + fc_b --------------------------
__global__ void k5_out(const float* __restrict__ pooled, const float* __restrict__ fcw,
                       const float* __restrict__ fcb, float* __restrict__ out) {
  int b = blockIdx.x, t = threadIdx.x;  // 64 threads
  float s = pooled[(b << 7) + t] * fcw[t] + pooled[(b << 7) + 64 + t] * fcw[64 + t];
  #pragma unroll
  for (int off = 1; off < 64; off <<= 1) s += __shfl_xor(s, off);
  if (t == 0) out[b] = s + fcb[0];
}

extern "C" void kernel_launch(void* const* d_in, const int* in_sizes, int n_in,
                              void* d_out, int out_size, void* d_ws, size_t ws_size,
                              hipStream_t stream) {
  const float* A    = (const float*)d_in[0];
  const float* H    = (const float*)d_in[1];
  const float* W    = (const float*)d_in[2];
  const float* bias = (const float*)d_in[3];
  const float* fcw  = (const float*)d_in[4];
  const float* fcb  = (const float*)d_in[5];
  float* out = (float*)d_out;

  float* ws = (float*)d_ws;
  float* partial = ws;                                   // 16*32*1024 f32 (2 MB)
  float* isd     = ws + 524288;                          // 32768 f32
  float* pooled  = ws + 524288 + 32768;                  // 4096 f32
  unsigned short* Wt   = (unsigned short*)(ws + 524288 + 32768 + 4096);   // 16384 bf16
  unsigned short* HWpT = Wt + 16384;                     // 32*128*1024 bf16 (8 MB)

  k1_colsum  <<<dim3(16, 32), 256, 0, stream>>>(A, partial);
  k2_finalize<<<128, 256, 0, stream>>>(partial, W, isd, pooled, Wt);
  k3_hw      <<<dim3(8, 32), 512, 0, stream>>>(H, Wt, isd, HWpT);
  k4_gcn     <<<dim3(16, 32), 256, 0, stream>>>(A, HWpT, isd, bias, pooled);
  k5_out     <<<32, 64, 0, stream>>>(pooled, fcw, fcb, out);
}

// Round 4
// 73.203 us; speedup vs baseline: 1.0537x; 1.0537x over previous
//
#include <hip/hip_runtime.h>
#include <hip/hip_bf16.h>

#define NB 32
#define NN 1024
#define FF 128

typedef __attribute__((ext_vector_type(8))) short short8;
typedef __attribute__((ext_vector_type(4))) float f32x4;

static __device__ __forceinline__ unsigned short f2bf(float x) {
  unsigned int u = __float_as_uint(x);
  u += 0x7fffu + ((u >> 16) & 1u);
  return (unsigned short)(u >> 16);
}

static __device__ __forceinline__ unsigned long long pack4bf(float a, float b, float c, float d) {
  return (unsigned long long)f2bf(a)
       | ((unsigned long long)f2bf(b) << 16)
       | ((unsigned long long)f2bf(c) << 32)
       | ((unsigned long long)f2bf(d) << 48);
}

static __device__ __forceinline__ void gl16(const void* g, void* l) {
  __builtin_amdgcn_global_load_lds((const __attribute__((address_space(1))) void*)g,
                                   (__attribute__((address_space(3))) void*)l, 16, 0, 0);
}

// ---- k1: column sums of A + write bf16 Atilde copy (identity added) ----------
__global__ __launch_bounds__(256) void k1_colsum_cvt(const float* __restrict__ A,
                                                     unsigned short* __restrict__ Ab,
                                                     float* __restrict__ partial) {
  int t = threadIdx.x;          // 0..255 -> columns 4t..4t+3
  int s = blockIdx.x;           // 0..15  -> rows s*64..s*64+63
  int b = blockIdx.y;           // 0..31
  const float* base = A + (size_t)b * NN * NN + (size_t)(s * 64) * NN + (t << 2);
  unsigned short* obase = Ab + (size_t)b * NN * NN + (size_t)(s * 64) * NN + (t << 2);
  int jj = t << 2;
  bool diag_band = ((t >> 4) == s);
  float4 sum = make_float4(0.f, 0.f, 0.f, 0.f);
  #pragma unroll 8
  for (int i = 0; i < 64; ++i) {
    float4 v = *reinterpret_cast<const float4*>(base + (size_t)i * NN);
    if (diag_band) {
      int gi = (s << 6) + i;
      v.x += (gi == jj)     ? 1.f : 0.f;
      v.y += (gi == jj + 1) ? 1.f : 0.f;
      v.z += (gi == jj + 2) ? 1.f : 0.f;
      v.w += (gi == jj + 3) ? 1.f : 0.f;
    }
    sum.x += v.x; sum.y += v.y; sum.z += v.z; sum.w += v.w;
    *reinterpret_cast<unsigned long long*>(obase + (size_t)i * NN) =
        pack4bf(v.x, v.y, v.z, v.w);
  }
  *reinterpret_cast<float4*>(partial + (((b << 4) + s) << 10) + jj) = sum;
}

// ---- k2: inv_sqrt_d, zero pooled, Wt = bf16(W^T) -----------------------------
__global__ void k2_finalize(const float* __restrict__ partial, const float* __restrict__ W,
                            float* __restrict__ isd, float* __restrict__ pooled,
                            unsigned short* __restrict__ Wt) {
  int idx = blockIdx.x * 256 + threadIdx.x;  // 0..32767
  int b = idx >> 10, j = idx & 1023;
  float d = 0.0f;   // identity's +1 already inside partial sums
  #pragma unroll
  for (int s = 0; s < 16; ++s) d += partial[(((b << 4) + s) << 10) + j];
  isd[idx] = rsqrtf(d);
  if (idx < 4096) pooled[idx] = 0.f;
  if (idx < 16384) {
    int o = idx >> 7, k = idx & 127;
    Wt[idx] = f2bf(W[k * FF + o]);   // Wt[o][k] = W[k][o]
  }
}

// ---- k3: HWpT[b][o][j] = bf16( isd[b,j] * sum_k W[k][o]*H[b][j][k] ) ---------
// Epilogue bounces D through LDS so global stores are 256B-coalesced rows.
__global__ __launch_bounds__(512) void k3_hw(const float* __restrict__ H,
                                             const unsigned short* __restrict__ Wt,
                                             const float* __restrict__ isd,
                                             unsigned short* __restrict__ HWpT) {
  __shared__ unsigned short Ws[128][136];
  __shared__ unsigned short Hs[128][136];
  int jblk = blockIdx.x;  // 0..7
  int b = blockIdx.y;     // 0..31
  int tid = threadIdx.x, wave = tid >> 6, lane = tid & 63;

  {
    int r = tid >> 4, c = (tid & 15) << 3;
    #pragma unroll
    for (int p = 0; p < 4; ++p) {
      int row = r + (p << 5);
      *reinterpret_cast<short8*>(&Ws[row][c]) =
          *reinterpret_cast<const short8*>(Wt + row * FF + c);
    }
  }
  {
    int r = tid >> 5, c = (tid & 31) << 2;
    const float* Hbase = H + (size_t)b * NN * FF + (size_t)(jblk * 128) * FF;
    #pragma unroll
    for (int p = 0; p < 8; ++p) {
      int row = r + (p << 4);
      const float4 v = *reinterpret_cast<const float4*>(Hbase + (size_t)row * FF + c);
      *reinterpret_cast<unsigned long long*>(&Hs[row][c]) = pack4bf(v.x, v.y, v.z, v.w);
    }
  }
  __syncthreads();

  f32x4 acc[8];
  #pragma unroll
  for (int i = 0; i < 8; ++i) acc[i] = (f32x4){0.f, 0.f, 0.f, 0.f};

  int mrow = (wave << 4) + (lane & 15);
  int koff = (lane >> 4) << 3;
  #pragma unroll
  for (int kk = 0; kk < 4; ++kk) {
    short8 af = *reinterpret_cast<const short8*>(&Ws[mrow][(kk << 5) + koff]);
    #pragma unroll
    for (int nf = 0; nf < 8; ++nf) {
      short8 bf = *reinterpret_cast<const short8*>(&Hs[(nf << 4) + (lane & 15)][(kk << 5) + koff]);
      acc[nf] = __builtin_amdgcn_mfma_f32_16x16x32_bf16(af, bf, acc[nf], 0, 0, 0);
    }
  }

  // write D (rows o = wave*16 + q*4 + r, cols j_local) into Ws (own rows only)
  int q = lane >> 4, l15 = lane & 15;
  #pragma unroll
  for (int nf = 0; nf < 8; ++nf) {
    int jl = (nf << 4) + l15;
    float sc = isd[(b << 10) + (jblk << 7) + jl];
    #pragma unroll
    for (int r = 0; r < 4; ++r) {
      Ws[(wave << 4) + (q << 2) + r][jl] = f2bf(acc[nf][r] * sc);
    }
  }
  __syncthreads();
  // coalesced store: 16 lanes cover 128 j-contiguous bf16 (256B) per o-row
  {
    unsigned short* obase = HWpT + (size_t)b * FF * NN + (size_t)(jblk * 128);
    int c8 = (tid & 15) << 3;
    #pragma unroll
    for (int p = 0; p < 4; ++p) {
      int o = (p << 5) + (tid >> 4);
      *reinterpret_cast<short8*>(obase + (size_t)o * NN + c8) =
          *reinterpret_cast<const short8*>(&Ws[o][c8]);
    }
  }
}

// ---- k4: h = relu(isd_i*(Ab@HWp')[i,f]+bias_f), fused sum-pool ---------------
// 128x128 tile, 4 waves (2x2), A: global_load_lds -> 3 rotating swizzled LDS
// buffers (depth-2); B: register double-buffer (depth-1). Raw s_barrier +
// counted vmcnt (never 0 in-loop).
__global__ __launch_bounds__(256) void k4_gcn(const unsigned short* __restrict__ Ab,
                                              const unsigned short* __restrict__ HWpT,
                                              const float* __restrict__ isd,
                                              const float* __restrict__ bias,
                                              float* __restrict__ pooled) {
  __shared__ __align__(1024) char ldsA[3 * 16384];   // 48 KB
  int fid = blockIdx.x;            // 0..255
  int nid = (fid & 7) * 32 + (fid >> 3);   // XCD-chunked: each XCD gets 4 b's
  int b = nid >> 3, iblk = nid & 7;
  int i0 = iblk << 7;
  int tid = threadIdx.x, wave = tid >> 6, lane = tid & 63;
  int wm = wave >> 1, wn = wave & 1;
  int l15 = lane & 15, q = lane >> 4;
  int q16 = q << 4;

  // A staging source (pre-swizzled chunk so linear LDS + XOR read line up)
  int r8 = lane >> 3;
  int ch = (lane & 7) ^ r8;
  const unsigned short* aS = Ab + (size_t)b * NN * NN
                           + (size_t)(i0 + (wave << 5) + r8) * NN + (ch << 3);
  char* aD0 = ldsA + (wave << 12);

  // B source: rows f = wn*64 + nf*16 + l15, 16B chunk q
  const unsigned short* bS = HWpT + (size_t)b * FF * NN
                           + (size_t)((wn << 6) + l15) * NN + (q << 3);

  f32x4 acc[4][4];
  #pragma unroll
  for (int m = 0; m < 4; ++m)
    #pragma unroll
    for (int n = 0; n < 4; ++n) acc[m][n] = (f32x4){0.f, 0.f, 0.f, 0.f};

  // fragment-read byte offsets (before kk/XOR): row = wm*64 + mr*16 + l15
  int swzR = (l15 & 7) << 4;
  int offA[4];
  #pragma unroll
  for (int mr = 0; mr < 4; ++mr)
    offA[mr] = ((wm << 6) + (mr << 4) + l15) * 128 + q16;

  short8 breg[2][4][2];

#define STAGE_A(buf, k0) { \
    const unsigned short* s_ = aS + (k0); \
    char* d_ = ldsA + (buf) * 16384 + (wave << 12); \
    gl16(s_,           d_); \
    gl16(s_ + 8 * NN,  d_ + 1024); \
    gl16(s_ + 16 * NN, d_ + 2048); \
    gl16(s_ + 24 * NN, d_ + 3072); }

#define LOAD_B(slot, k0) { \
    _Pragma("unroll") \
    for (int nf_ = 0; nf_ < 4; ++nf_) { \
      _Pragma("unroll") \
      for (int kk_ = 0; kk_ < 2; ++kk_) \
        breg[slot][nf_][kk_] = *reinterpret_cast<const short8*>( \
            bS + (size_t)(nf_ << 4) * NN + (k0) + (kk_ << 5)); } }

  // prologue: A(0), A(1), B(0)
  STAGE_A(0, 0)
  STAGE_A(1, 64)
  LOAD_B(0, 0)

  #pragma unroll
  for (int t = 0; t < 16; ++t) {
    if (t < 15) LOAD_B((t + 1) & 1, (t + 1) * 64)
    if (t < 14) STAGE_A((t + 2) % 3, (t + 2) * 64)
    // wait: A(t) and B(t) complete; keep A(t+1), B(t+1), A(t+2) in flight
    if (t < 14)      asm volatile("s_waitcnt vmcnt(16)" ::: "memory");
    else if (t == 14) asm volatile("s_waitcnt vmcnt(12)" ::: "memory");
    else              asm volatile("s_waitcnt vmcnt(0)" ::: "memory");
    __builtin_amdgcn_s_barrier();
    const char* Abuf = ldsA + (t % 3) * 16384;
    #pragma unroll
    for (int kk = 0; kk < 2; ++kk) {
      short8 af[4];
      #pragma unroll
      for (int mr = 0; mr < 4; ++mr)
        af[mr] = *reinterpret_cast<const short8*>(Abuf + ((offA[mr] + (kk << 6)) ^ swzR));
      #pragma unroll
      for (int mr = 0; mr < 4; ++mr)
        #pragma unroll
        for (int nf = 0; nf < 4; ++nf)
          acc[mr][nf] = __builtin_amdgcn_mfma_f32_16x16x32_bf16(
              af[mr], breg[t & 1][nf][kk], acc[mr][nf], 0, 0, 0);
    }
    __builtin_amdgcn_s_barrier();
  }
#undef STAGE_A
#undef LOAD_B

  // epilogue: rows i = i0 + wm*64 + mr*16 + q*4 + r ; cols f = wn*64+nf*16+l15
  #pragma unroll
  for (int nf = 0; nf < 4; ++nf) {
    int f = (wn << 6) + (nf << 4) + l15;
    float bi = bias[f];
    float stot = 0.f;
    #pragma unroll
    for (int mr = 0; mr < 4; ++mr) {
      int irow = i0 + (wm << 6) + (mr << 4) + (q << 2);
      const f32x4 sc = *reinterpret_cast<const f32x4*>(isd + (b << 10) + irow);
      stot += fmaxf(acc[mr][nf][0] * sc[0] + bi, 0.f)
            + fmaxf(acc[mr][nf][1] * sc[1] + bi, 0.f)
            + fmaxf(acc[mr][nf][2] * sc[2] + bi, 0.f)
            + fmaxf(acc[mr][nf][3] * sc[3] + bi, 0.f);
    }
    stot += __shfl_xor(stot, 16);
    stot += __shfl_xor(stot, 32);
    if (lane < 16) atomicAdd(&pooled[(b << 7) + f], stot);
  }
}

// ---- k5: out[b] = sum_f pooled[b][f]*fc_w[f] + fc_b --------------------------
__global__ void k5_out(const float* __restrict__ pooled, const float* __restrict__ fcw,
                       const float* __restrict__ fcb, float* __restrict__ out) {
  int b = blockIdx.x, t = threadIdx.x;  // 64 threads
  float s = pooled[(b << 7) + t] * fcw[t] + pooled[(b << 7) + 64 + t] * fcw[64 + t];
  #pragma unroll
  for (int off = 1; off < 64; off <<= 1) s += __shfl_xor(s, off);
  if (t == 0) out[b] = s + fcb[0];
}

extern "C" void kernel_launch(void* const* d_in, const int* in_sizes, int n_in,
                              void* d_out, int out_size, void* d_ws, size_t ws_size,
                              hipStream_t stream) {
  const float* A    = (const float*)d_in[0];
  const float* H    = (const float*)d_in[1];
  const float* W    = (const float*)d_in[2];
  const float* bias = (const float*)d_in[3];
  const float* fcw  = (const float*)d_in[4];
  const float* fcb  = (const float*)d_in[5];
  float* out = (float*)d_out;

  float* ws = (float*)d_ws;
  float* partial = ws;                                   // 16*32*1024 f32 (2 MB)
  float* isd     = ws + 524288;                          // 32768 f32
  float* pooled  = ws + 524288 + 32768;                  // 4096 f32
  unsigned short* Wt   = (unsigned short*)(ws + 524288 + 32768 + 4096);   // 16384 bf16
  unsigned short* HWpT = Wt + 16384;                     // 32*128*1024 bf16 (8 MB)
  unsigned short* Ab   = HWpT + (size_t)NB * FF * NN;    // 32*1024*1024 bf16 (64 MB)

  k1_colsum_cvt<<<dim3(16, 32), 256, 0, stream>>>(A, Ab, partial);
  k2_finalize  <<<128, 256, 0, stream>>>(partial, W, isd, pooled, Wt);
  k3_hw        <<<dim3(8, 32), 512, 0, stream>>>(H, Wt, isd, HWpT);
  k4_gcn       <<<256, 256, 0, stream>>>(Ab, HWpT, isd, bias, pooled);
  k5_out       <<<32, 64, 0, stream>>>(pooled, fcw, fcb, out);
}